// Round 1
// 601.333 us; speedup vs baseline: 1.0017x; 1.0017x over previous
//
#include <hip/hip_runtime.h>
#include <hip/hip_cooperative_groups.h>

namespace cg = cooperative_groups;

// WaveNet residual stack — round 10: single cooperative persistent kernel.
//  - 512 blocks (16 batches x 32 tiles of 256 cols, absolute-indexed), 4 waves,
//    2 blocks/CU (80 KB LDS, launch_bounds(256,2)).
//  - Skip accumulator lives in registers (f32x4[2][16] per lane) across all 16
//    layers: g never spills to HBM, skip written once. Stream ping-pongs via
//    bufA/bufB with grid.sync() per layer (replaces kernel-boundary sync).
//  - Traffic: ~2.9 GB (r9 aggregate) -> ~1.3 GB. Numerics identical to r9
//    (same frag layouts, bf16 conv inputs, fp32 residual add, bf16 g).
//  - Fallback: if cooperative co-residency check fails, run the verified r9
//    multi-kernel path unchanged.
// MFMA layouts (HW-verified): A[m=lane&15][k=quad*8+j], B[k=quad*8+j][n=lane&15],
// C/D col=lane&15 row=quad*4+reg.

#define NBATCH 16
#define C 64
#define SC 128
#define L0 8192
#define OSIZE 7682
#define TILE 64
#define ST 128
#define FT 256                              // fused: columns per block
#define FW 384                              // FT + max dilation (128)
#define FSMEM (8*FW*8*2 + 8*FT*8*2)         // 49152 + 32768 = 81920 B

typedef __bf16 bf16x8 __attribute__((ext_vector_type(8)));
typedef __bf16 bf16x4 __attribute__((ext_vector_type(4)));
typedef float  f32x4  __attribute__((ext_vector_type(4)));

// ---- pre-pass: pack weights to bf16, k-contiguous MFMA A-layout ----
__global__ __launch_bounds__(256) void pack_weights(
    const float* __restrict__ Wd, const float* __restrict__ Wr,
    const float* __restrict__ Ws,
    __bf16* __restrict__ Wdm, __bf16* __restrict__ Wrm, __bf16* __restrict__ Wsm)
{
    int idx = blockIdx.x * 256 + threadIdx.x;
    if (idx < 131072) {                       // Wdm[ly][o][kp]: kp<64 tap0, else tap1
        int kp = idx & 127, o = (idx >> 7) & 63, ly = idx >> 13;
        int k = kp & 63, tap = kp >> 6;
        Wdm[idx] = (__bf16)Wd[(((ly * 64 + o) * 64 + k) << 1) + tap];
    } else if (idx < 196608) {                // Wrm[ly][o][k]
        int j = idx - 131072;
        Wrm[j] = (__bf16)Wr[j];
    } else if (idx < 327680) {                // Wsm[ly][s][k]
        int j = idx - 196608;
        Wsm[j] = (__bf16)Ws[j];
    }
}

// ======================= fused cooperative kernel =======================
__global__ __launch_bounds__(256, 2) void wavenet_fused(
    const float* __restrict__ x,
    float* __restrict__ bufA, float* __restrict__ bufB,
    const __bf16* __restrict__ Wdm, const __bf16* __restrict__ Wrm,
    const __bf16* __restrict__ Wsm,
    float* __restrict__ out, float* __restrict__ skip)
{
    extern __shared__ char smem[];
    __bf16* sxp = (__bf16*)smem;                  // [8][FW][8] k-packed conv input
    __bf16* sgp = (__bf16*)(smem + 8 * FW * 8 * 2); // [8][FT][8] k-packed gate out

    cg::grid_group gg = cg::this_grid();

    const int blk = blockIdx.x;
    const int n   = blk >> 5;                // 32 tiles per batch
    const int a   = (blk & 31) * FT;         // absolute column base
    const int t    = threadIdx.x;
    const int lane = t & 63;
    const int wv   = t >> 6;
    const int q    = lane >> 4;
    const int nn   = lane & 15;

    // persistent skip accumulator: rows wv*32+mt*16+q*4+r, col a+nt*16+nn
    f32x4 accS[2][16];
    #pragma unroll
    for (int mt = 0; mt < 2; ++mt)
        #pragma unroll
        for (int nt = 0; nt < 16; ++nt)
            accS[mt][nt] = (f32x4){0.f, 0.f, 0.f, 0.f};

    const float* src = x;

    for (int ly = 0; ly < 16; ++ly) {
        const int d = 1 << (ly & 7);
        const int W = FT + d;

        // ---- stage src[a-d, a+FT) -> bf16 k-packed LDS ----
        // cols s<0 clamp to 0: they only feed the garbage region s<D_{ly+1},
        // which is never read downstream and masked at all output writes.
        for (int kg = 0; kg < 8; ++kg) {
            for (int j = t; j < W; j += 256) {
                int s = a - d + j;
                if (s < 0) s = 0;
                const float* col = src + (size_t)(n * C + kg * 8) * L0 + s;
                bf16x8 bv;
                #pragma unroll
                for (int jj = 0; jj < 8; ++jj) bv[jj] = (__bf16)col[(size_t)jj * L0];
                *(bf16x8*)(sxp + ((size_t)kg * FW + j) * 8) = bv;
            }
        }
        __syncthreads();

        // ---- conv y[s] = Wd0@x[s-d] + Wd1@x[s] (K'=128), gate -> sgp ----
        const __bf16* arow = Wdm + ((size_t)ly * 64 + (wv * 16 + nn)) * 128 + q * 8;
        bf16x8 aW0 = *(const bf16x8*)(arow);
        bf16x8 aW1 = *(const bf16x8*)(arow + 32);
        bf16x8 aW2 = *(const bf16x8*)(arow + 64);
        bf16x8 aW3 = *(const bf16x8*)(arow + 96);
        #pragma unroll 4
        for (int nt = 0; nt < 16; ++nt) {
            int p = nt * 16 + nn;
            f32x4 acc = {0.f, 0.f, 0.f, 0.f};
            acc = __builtin_amdgcn_mfma_f32_16x16x32_bf16(aW0,
                    *(const bf16x8*)(sxp + ((size_t)(q    ) * FW + p    ) * 8), acc, 0, 0, 0);
            acc = __builtin_amdgcn_mfma_f32_16x16x32_bf16(aW1,
                    *(const bf16x8*)(sxp + ((size_t)(4 + q) * FW + p    ) * 8), acc, 0, 0, 0);
            acc = __builtin_amdgcn_mfma_f32_16x16x32_bf16(aW2,
                    *(const bf16x8*)(sxp + ((size_t)(q    ) * FW + p + d) * 8), acc, 0, 0, 0);
            acc = __builtin_amdgcn_mfma_f32_16x16x32_bf16(aW3,
                    *(const bf16x8*)(sxp + ((size_t)(4 + q) * FW + p + d) * 8), acc, 0, 0, 0);
            bf16x4 gv;
            #pragma unroll
            for (int r = 0; r < 4; ++r) {
                float y = fminf(fmaxf(acc[r], -20.f), 20.f);
                float u = __expf(y);
                gv[r] = (__bf16)(u * (u - 1.f) / fmaf(u, u, 1.f));
            }
            *(bf16x4*)(sgp + ((size_t)(2 * wv + (q >> 1)) * FT + p) * 8 + (q & 1) * 4) = gv;
        }
        __syncthreads();

        // ---- res = Wr@g + src[s]  (residual add re-reads global; L2-hot) ----
        const __bf16* rrow = Wrm + ((size_t)ly * 64 + (wv * 16 + nn)) * 64 + q * 8;
        bf16x8 aR0 = *(const bf16x8*)rrow;
        bf16x8 aR1 = *(const bf16x8*)(rrow + 32);
        float* dst = (ly & 1) ? bufB : bufA;
        #pragma unroll 4
        for (int nt = 0; nt < 16; ++nt) {
            int p = nt * 16 + nn;
            f32x4 acc = {0.f, 0.f, 0.f, 0.f};
            acc = __builtin_amdgcn_mfma_f32_16x16x32_bf16(aR0,
                    *(const bf16x8*)(sgp + ((size_t)(q    ) * FT + p) * 8), acc, 0, 0, 0);
            acc = __builtin_amdgcn_mfma_f32_16x16x32_bf16(aR1,
                    *(const bf16x8*)(sgp + ((size_t)(4 + q) * FT + p) * 8), acc, 0, 0, 0);
            int s = a + p;
            if (ly == 15) {
                if (s >= 510) {
                    #pragma unroll
                    for (int r = 0; r < 4; ++r) {
                        int ch = wv * 16 + q * 4 + r;
                        out[(size_t)(n * C + ch) * OSIZE + (s - 510)]
                            = acc[r] + src[(size_t)(n * C + ch) * L0 + s];
                    }
                }
            } else {
                #pragma unroll
                for (int r = 0; r < 4; ++r) {
                    int ch = wv * 16 + q * 4 + r;
                    dst[(size_t)(n * C + ch) * L0 + s]
                        = acc[r] + src[(size_t)(n * C + ch) * L0 + s];
                }
            }
        }

        // ---- skip += Ws@g into persistent registers (sgp is read-only here;
        //      the post-stage barrier of the next layer orders reuse) ----
        const __bf16* srow = Wsm + (size_t)ly * SC * 64;
        bf16x8 aS00 = *(const bf16x8*)(srow + (size_t)(wv * 32 +      nn) * 64 +      q * 8);
        bf16x8 aS01 = *(const bf16x8*)(srow + (size_t)(wv * 32 +      nn) * 64 + 32 + q * 8);
        bf16x8 aS10 = *(const bf16x8*)(srow + (size_t)(wv * 32 + 16 + nn) * 64 +      q * 8);
        bf16x8 aS11 = *(const bf16x8*)(srow + (size_t)(wv * 32 + 16 + nn) * 64 + 32 + q * 8);
        #pragma unroll
        for (int nt = 0; nt < 16; ++nt) {
            int p = nt * 16 + nn;
            bf16x8 b0 = *(const bf16x8*)(sgp + ((size_t)(q    ) * FT + p) * 8);
            bf16x8 b1 = *(const bf16x8*)(sgp + ((size_t)(4 + q) * FT + p) * 8);
            accS[0][nt] = __builtin_amdgcn_mfma_f32_16x16x32_bf16(aS00, b0, accS[0][nt], 0, 0, 0);
            accS[0][nt] = __builtin_amdgcn_mfma_f32_16x16x32_bf16(aS01, b1, accS[0][nt], 0, 0, 0);
            accS[1][nt] = __builtin_amdgcn_mfma_f32_16x16x32_bf16(aS10, b0, accS[1][nt], 0, 0, 0);
            accS[1][nt] = __builtin_amdgcn_mfma_f32_16x16x32_bf16(aS11, b1, accS[1][nt], 0, 0, 0);
        }

        src = dst;
        if (ly < 15) gg.sync();      // stream handoff between layers
    }

    // ---- write skip exactly once ----
    #pragma unroll
    for (int mt = 0; mt < 2; ++mt)
        #pragma unroll
        for (int nt = 0; nt < 16; ++nt) {
            int s = a + nt * 16 + nn;
            if (s >= 510) {
                #pragma unroll
                for (int r = 0; r < 4; ++r) {
                    int sch = wv * 32 + mt * 16 + q * 4 + r;
                    skip[(size_t)(n * SC + sch) * OSIZE + (s - 510)] = accS[mt][nt][r];
                }
            }
        }
}

// ======================= r9 fallback kernels (verbatim) =======================
__global__ __launch_bounds__(256) void wavenet_layer_mfma(
    const float* __restrict__ src, int src_stride, int Lin,
    float* __restrict__ dst, int dst_stride,
    const __bf16* __restrict__ Wdm,   // [64][128]
    const __bf16* __restrict__ Wrm,   // [64][64]
    __bf16* __restrict__ gout,        // [NBATCH][8][OSIZE][8] this layer's slot
    int d)
{
    extern __shared__ char smem_raw[];
    const int W    = TILE + d;
    const int Lout = Lin - d;
    const int n  = blockIdx.y;
    const int l0 = blockIdx.x * TILE;
    if (l0 >= Lout) return;
    const int np = min(TILE, Lout - l0);

    __bf16* sxp  = (__bf16*)smem_raw;                          // [8][W][8] k-packed
    float*  sres = (float*)(smem_raw + (size_t)8 * W * 8 * 2); // [64][65] fp32
    __bf16* sgp  = (__bf16*)(sres + 64 * 65);                  // [8][64][8] k-packed

    const int t    = threadIdx.x;
    const int lane = t & 63;
    const int wv   = t >> 6;
    const int q    = lane >> 4;
    const int nn   = lane & 15;

    for (int item = t; item < 8 * W; item += 256) {
        int kg = item / W;
        int p  = item % W;
        bool inb = (l0 + p) < Lin;
        const float* col = src + (size_t)(n * C + kg * 8) * src_stride + l0 + p;
        float v[8];
        #pragma unroll
        for (int j = 0; j < 8; ++j) v[j] = inb ? col[(size_t)j * src_stride] : 0.f;
        bf16x8 bv;
        #pragma unroll
        for (int j = 0; j < 8; ++j) bv[j] = (__bf16)v[j];
        *(bf16x8*)(sxp + ((size_t)kg * W + p) * 8) = bv;
        int pr = p - d;
        if (pr >= 0 && pr < TILE) {
            #pragma unroll
            for (int j = 0; j < 8; ++j) sres[(kg * 8 + j) * 65 + pr] = v[j];
        }
    }
    __syncthreads();

    const __bf16* arow = Wdm + (size_t)(wv * 16 + nn) * 128 + q * 8;
    bf16x8 aW[4];
    #pragma unroll
    for (int ks = 0; ks < 4; ++ks) aW[ks] = *(const bf16x8*)(arow + ks * 32);

    #pragma unroll
    for (int nt = 0; nt < 4; ++nt) {
        int p0 = nt * 16;
        f32x4 acc = {0.f, 0.f, 0.f, 0.f};
        acc = __builtin_amdgcn_mfma_f32_16x16x32_bf16(aW[0],
                *(const bf16x8*)(sxp + ((size_t)(q    ) * W + p0 + nn    ) * 8), acc, 0, 0, 0);
        acc = __builtin_amdgcn_mfma_f32_16x16x32_bf16(aW[1],
                *(const bf16x8*)(sxp + ((size_t)(4 + q) * W + p0 + nn    ) * 8), acc, 0, 0, 0);
        acc = __builtin_amdgcn_mfma_f32_16x16x32_bf16(aW[2],
                *(const bf16x8*)(sxp + ((size_t)(q    ) * W + p0 + nn + d) * 8), acc, 0, 0, 0);
        acc = __builtin_amdgcn_mfma_f32_16x16x32_bf16(aW[3],
                *(const bf16x8*)(sxp + ((size_t)(4 + q) * W + p0 + nn + d) * 8), acc, 0, 0, 0);
        bf16x4 gv;
        #pragma unroll
        for (int r = 0; r < 4; ++r) {
            float y = fminf(fmaxf(acc[r], -20.f), 20.f);
            float u = __expf(y);
            gv[r] = (__bf16)(u * (u - 1.f) / fmaf(u, u, 1.f));
        }
        *(bf16x4*)(sgp + ((size_t)(2 * wv + (q >> 1)) * 64 + p0 + nn) * 8 + (q & 1) * 4) = gv;
    }
    __syncthreads();

    const __bf16* rrow = Wrm + (size_t)(wv * 16 + nn) * 64 + q * 8;
    bf16x8 aR0 = *(const bf16x8*)rrow;
    bf16x8 aR1 = *(const bf16x8*)(rrow + 32);
    #pragma unroll
    for (int nt = 0; nt < 4; ++nt) {
        int p0 = nt * 16;
        f32x4 acc = {0.f, 0.f, 0.f, 0.f};
        acc = __builtin_amdgcn_mfma_f32_16x16x32_bf16(aR0,
                *(const bf16x8*)(sgp + ((size_t)(q    ) * 64 + p0 + nn) * 8), acc, 0, 0, 0);
        acc = __builtin_amdgcn_mfma_f32_16x16x32_bf16(aR1,
                *(const bf16x8*)(sgp + ((size_t)(4 + q) * 64 + p0 + nn) * 8), acc, 0, 0, 0);
        if (p0 + nn < np) {
            #pragma unroll
            for (int r = 0; r < 4; ++r) {
                int ch = wv * 16 + q * 4 + r;
                dst[(size_t)(n * C + ch) * dst_stride + l0 + p0 + nn]
                    = acc[r] + sres[ch * 65 + p0 + nn];
            }
        }
    }

    const int sbase = Lout - OSIZE;
    for (int item = t; item < 8 * TILE; item += 256) {
        int p  = item & 63;
        int kg = item >> 6;
        int l  = l0 + p;
        if (l >= sbase && l < Lout) {
            *(bf16x8*)(gout + (((size_t)n * 8 + kg) * OSIZE + (l - sbase)) * 8)
                = *(const bf16x8*)(sgp + ((size_t)kg * 64 + p) * 8);
        }
    }
}

__global__ __launch_bounds__(256) void skip_gemm(
    const __bf16* __restrict__ g,     // [G][NBATCH][8][OSIZE][8]
    const __bf16* __restrict__ Wsm,   // [16][128][64]
    float* __restrict__ skip,         // [NBATCH][128][OSIZE]
    int G, int lybase, int init)
{
    __shared__ __bf16 Bb[8][ST][8];
    const int n  = blockIdx.y;
    const int l0 = blockIdx.x * ST;
    const int t  = threadIdx.x;
    const int lane = t & 63;
    const int wv   = __builtin_amdgcn_readfirstlane(t >> 6);
    const int q = lane >> 4, nn = lane & 15;

    f32x4 acc[2][8];
    #pragma unroll
    for (int mt = 0; mt < 2; ++mt)
        #pragma unroll
        for (int nt = 0; nt < 8; ++nt) acc[mt][nt] = (f32x4){0.f, 0.f, 0.f, 0.f};

    for (int gi = 0; gi < G; ++gi) {
        const __bf16* gl = g + ((size_t)gi * NBATCH + n) * (size_t)8 * OSIZE * 8;
        #pragma unroll
        for (int j = 0; j < 4; ++j) {
            int kg   = 2 * wv + (j >> 1);
            int half = j & 1;
            const __bf16* srcp = gl + ((size_t)kg * OSIZE + l0 + half * 64) * 8
                                    + (size_t)lane * 8;
            __builtin_amdgcn_global_load_lds(
                (const __attribute__((address_space(1))) void*)srcp,
                (__attribute__((address_space(3))) void*)&Bb[kg][half * 64][0],
                16, 0, 0);
        }
        const __bf16* Wl = Wsm + (size_t)(lybase + gi) * SC * 64;
        bf16x8 a00 = *(const bf16x8*)(Wl + (size_t)(wv * 32 +      nn) * 64 +  0 + q * 8);
        bf16x8 a01 = *(const bf16x8*)(Wl + (size_t)(wv * 32 +      nn) * 64 + 32 + q * 8);
        bf16x8 a10 = *(const bf16x8*)(Wl + (size_t)(wv * 32 + 16 + nn) * 64 +  0 + q * 8);
        bf16x8 a11 = *(const bf16x8*)(Wl + (size_t)(wv * 32 + 16 + nn) * 64 + 32 + q * 8);
        __syncthreads();
        #pragma unroll
        for (int ks = 0; ks < 2; ++ks) {
            #pragma unroll
            for (int nt = 0; nt < 8; ++nt) {
                bf16x8 b = *(const bf16x8*)&Bb[ks * 4 + q][nt * 16 + nn][0];
                acc[0][nt] = __builtin_amdgcn_mfma_f32_16x16x32_bf16(
                                 ks ? a01 : a00, b, acc[0][nt], 0, 0, 0);
                acc[1][nt] = __builtin_amdgcn_mfma_f32_16x16x32_bf16(
                                 ks ? a11 : a10, b, acc[1][nt], 0, 0, 0);
            }
        }
        __syncthreads();
    }

    #pragma unroll
    for (int mt = 0; mt < 2; ++mt)
        #pragma unroll
        for (int nt = 0; nt < 8; ++nt) {
            int p = l0 + nt * 16 + nn;
            if (p < OSIZE) {
                #pragma unroll
                for (int r = 0; r < 4; ++r) {
                    int s = wv * 32 + mt * 16 + q * 4 + r;
                    size_t idx = ((size_t)n * SC + s) * OSIZE + p;
                    float v = acc[mt][nt][r];
                    skip[idx] = init ? v : (skip[idx] + v);
                }
            }
        }
}

extern "C" void kernel_launch(void* const* d_in, const int* in_sizes, int n_in,
                              void* d_out, int out_size, void* d_ws, size_t ws_size,
                              hipStream_t stream) {
    const float* x      = (const float*)d_in[0];
    const float* W_dil  = (const float*)d_in[1];
    const float* W_res  = (const float*)d_in[2];
    const float* W_skip = (const float*)d_in[3];

    float* out  = (float*)d_out;                        // [16][64][7682]
    float* skip = out + (size_t)NBATCH * C * OSIZE;     // [16][128][7682]

    float*  bufA = (float*)d_ws;
    float*  bufB = bufA + (size_t)NBATCH * C * L0;
    __bf16* Wdm  = (__bf16*)(bufB + (size_t)NBATCH * C * L0);
    __bf16* Wrm  = Wdm + 16 * 64 * 128;
    __bf16* Wsm  = Wrm + 16 * 64 * 64;
    __bf16* gst  = Wsm + 16 * 128 * 64;

    // one-time host-side co-residency check (no stream ops; capture-safe)
    static int use_coop = -1;
    if (use_coop < 0) {
        int dev = 0, coop = 0, nb = 0;
        hipGetDevice(&dev);
        hipDeviceGetAttribute(&coop, hipDeviceAttributeCooperativeLaunch, dev);
        hipError_t e = hipOccupancyMaxActiveBlocksPerMultiprocessor(
            &nb, (const void*)wavenet_fused, 256, FSMEM);
        use_coop = (coop && e == hipSuccess && nb >= 2) ? 1 : 0;
    }

    pack_weights<<<1280, 256, 0, stream>>>(W_dil, W_res, W_skip, Wdm, Wrm, Wsm);

    if (use_coop) {
        void* args[] = { (void*)&x, (void*)&bufA, (void*)&bufB,
                         (void*)&Wdm, (void*)&Wrm, (void*)&Wsm,
                         (void*)&out, (void*)&skip };
        hipLaunchCooperativeKernel((const void*)wavenet_fused,
                                   dim3(NBATCH * (L0 / FT)), dim3(256),
                                   args, FSMEM, stream);
        return;
    }

    // ---- fallback: verified r9 multi-kernel path ----
    const size_t slotHW = (size_t)NBATCH * 8 * OSIZE * 8;
    const size_t used   = (size_t)((char*)gst - (char*)d_ws);
    int G = 16;
    while (G > 1 && used + (size_t)G * slotHW * 2 + 65536 > ws_size) G >>= 1;

    const float* src = x;
    int src_stride = L0, Lin = L0;
    float* bufs[2] = {bufA, bufB};

    for (int i = 0; i < 16; ++i) {
        int d    = 1 << (i & 7);
        int Lout = Lin - d;
        float* dst;
        int dst_stride;
        if (i == 15) { dst = out;         dst_stride = OSIZE; }
        else         { dst = bufs[i & 1]; dst_stride = L0;    }

        int W = TILE + d;
        size_t smem = (size_t)128 * W + 64 * 65 * 4 + 8 * 64 * 8 * 2;

        dim3 grid((Lout + TILE - 1) / TILE, NBATCH);
        wavenet_layer_mfma<<<grid, 256, smem, stream>>>(
            src, src_stride, Lin, dst, dst_stride,
            Wdm + (size_t)i * 64 * 128,
            Wrm + (size_t)i * 64 * 64,
            gst + (size_t)(i % G) * slotHW,
            d);

        if (((i + 1) % G) == 0) {
            dim3 sgrid((OSIZE + ST - 1) / ST, NBATCH);
            skip_gemm<<<sgrid, 256, 0, stream>>>(
                gst, Wsm, skip, G, i + 1 - G, (i + 1 == G) ? 1 : 0);
        }

        src = dst;
        src_stride = dst_stride;
        Lin = Lout;
    }
}